// Round 11
// baseline (193.282 us; speedup 1.0000x reference)
//
#include <hip/hip_runtime.h>
#include <hip/hip_bf16.h>
#include <cstdint>
#include <cstddef>

typedef short short8 __attribute__((ext_vector_type(8)));
typedef float f32x4 __attribute__((ext_vector_type(4)));
typedef float f32x2 __attribute__((ext_vector_type(2)));

#define NS    2048
#define KPAD  288
#define H2    512
#define HID   256
#define WPB   7       // windows per sig workgroup (192 thr = 3 waves = 3 thirds)
#define SBLK  293     // ceil(2048/7)
#define KLDS1 296     // 288 padded: stride 148 dw = 20 mod 32 -> 2-way (free)
#define KLDS2 520     // 512 padded: stride 260 dw =  4 mod 32 -> 2-way (free)

#define MFMA(a,b,c) __builtin_amdgcn_mfma_f32_16x16x32_bf16((a),(b),(c),0,0,0)

__device__ __forceinline__ float geluf(float x) {
    return 0.5f * x * (1.0f + erff(x * 0.70710678118654752f));
}
__device__ __forceinline__ f32x4 shfl4(f32x4 v, int d) {
    f32x4 r;
    r[0] = __shfl_xor(v[0], d); r[1] = __shfl_xor(v[1], d);
    r[2] = __shfl_xor(v[2], d); r[3] = __shfl_xor(v[3], d);
    return r;
}

struct Tbl3 { short col[729]; };
static constexpr Tbl3 make_tbl3() {
    Tbl3 t{};
    for (int x = 0; x < 729; ++x) t.col[x] = -1;
    int r = 0;
    for (int i = 0; i < 9; ++i)
        for (int j = 0; j < 9; ++j)
            for (int k = 0; k < 9; ++k) {
                bool lt1 = (i < j) || (i == j && (j < k || (j == k && k < i)));
                bool lt2 = (i < k) || (i == k && (j < i || (j == i && k < j)));
                if (lt1 && lt2) { t.col[(i*9+j)*9+k] = (short)(45 + r); ++r; }
            }
    return t;
}
static constexpr Tbl3 TBL3 = make_tbl3();

// ============================================================================
// sig kernel: UNCHANGED from r10 (measured 44.7us).
// ============================================================================
#define SIG_STEP(VA_,VB_,VC_) { \
    const float hh = 0.5f * S1i + vi * (1.0f/6.0f); \
    const float ra = S2ra + hh * (VA_); \
    const float rb = S2rb + hh * (VB_); \
    const float rc = S2rc + hh * (VC_); \
    const f32x2 ra2 = {ra, ra}, rb2 = {rb, rb}, rc2 = {rc, rc}; \
    S3sa += ra * v0; S3pa0 += ra2*vp0; S3pa1 += ra2*vp1; S3pa2 += ra2*vp2; S3pa3 += ra2*vp3; \
    S3sb += rb * v0; S3pb0 += rb2*vp0; S3pb1 += rb2*vp1; S3pb2 += rb2*vp2; S3pb3 += rb2*vp3; \
    S3sc += rc * v0; S3pc0 += rc2*vp0; S3pc1 += rc2*vp1; S3pc2 += rc2*vp2; S3pc3 += rc2*vp3; \
    const float aa = S1i + 0.5f * vi; \
    S2ra += aa * (VA_); S2rb += aa * (VB_); S2rc += aa * (VC_); \
    S1i += vi; }

#define SIG_MAIN(VA_,VB_,VC_) { \
    { const float* xr = &X[(g0 - lo) * 8]; \
      const float4 e0 = *(const float4*)xr; \
      const float4 e1 = *(const float4*)(xr + 4); \
      const float rs = xr[ioff]; \
      const float v0 = 0.0f; \
      const f32x2 vp0 = {e0.x, e0.y}, vp1 = {e0.z, e0.w}, vp2 = {e1.x, e1.y}, vp3 = {e1.z, e1.w}; \
      const float vi = (ci == 0) ? 0.0f : rs; \
      SIG_STEP(VA_,VB_,VC_) } \
    const float* pd = &PD[(sm59 + 1 - lo + 59) * 8]; \
    float4 d0 = *(const float4*)pd; \
    float4 d1 = *(const float4*)(pd + 4); \
    float rn = pd[ioff]; \
    _Pragma("unroll 4") \
    for (int j = 1; j < 60; ++j) { \
      const float4 e0 = d0; const float4 e1 = d1; const float rs = rn; \
      pd += 8; \
      d0 = *(const float4*)pd; d1 = *(const float4*)(pd + 4); rn = pd[ioff]; \
      const float v0 = DT; \
      const f32x2 vp0 = {e0.x, e0.y}, vp1 = {e0.z, e0.w}, vp2 = {e1.x, e1.y}, vp3 = {e1.z, e1.w}; \
      const float vi = (ci == 0) ? DT : rs; \
      SIG_STEP(VA_,VB_,VC_) \
    } }

#define SIG_ST(RA,RB,RC) \
    if (act) { \
        if ((RA) == 0) S1buf[widx * 9 + ci] = S1i; \
        float* sb = &S2buf[widx * 81 + ci * 9]; \
        sb[RA] = S2ra; sb[RB] = S2rb; sb[RC] = S2rc; \
    }

#define S3EL0(SL) S3s##SL
#define S3EL1(SL) S3p##SL##0[0]
#define S3EL2(SL) S3p##SL##0[1]
#define S3EL3(SL) S3p##SL##1[0]
#define S3EL4(SL) S3p##SL##1[1]
#define S3EL5(SL) S3p##SL##2[0]
#define S3EL6(SL) S3p##SL##2[1]
#define S3EL7(SL) S3p##SL##3[0]
#define S3EL8(SL) S3p##SL##3[1]

#define SIG_E2(SL,J2) if (ci < (J2)) { \
    const float val2 = S2r##SL - 0.5f * S1i * s1v##J2; \
    const int col2 = 9 + ci*8 - (ci*(ci-1))/2 + ((J2) - ci - 1); \
    frow[col2] = __float2bfloat16(val2); }

#define SIG_E3(SL,R,K) { const int col3 = TBL3.col[tb + (R)*9 + (K)]; \
    if (col3 >= 0) { \
        const float val3 = S3EL##K(SL) \
            - 0.5f * (S1i * S2w[(R)*9+(K)] + S2r##SL * s1v##K) \
            + S1i * s1v##R * s1v##K * (1.0f/3.0f); \
        frow[col3] = __float2bfloat16(val3); } }

#define SIG_E3R(SL,R) SIG_E3(SL,R,0) SIG_E3(SL,R,1) SIG_E3(SL,R,2) SIG_E3(SL,R,3) \
    SIG_E3(SL,R,4) SIG_E3(SL,R,5) SIG_E3(SL,R,6) SIG_E3(SL,R,7) SIG_E3(SL,R,8)

#define SIG_EMIT(RA,RB,RC) \
    if (act) { \
        if ((RA) == 0) { \
            frow[ci] = __float2bfloat16(S1i); \
            if (ci == 0) { \
                const __hip_bfloat16 z16 = __float2bfloat16(0.0f); \
                frow[285] = z16; frow[286] = z16; frow[287] = z16; \
            } \
        } \
        SIG_E2(a,RA) SIG_E2(b,RB) SIG_E2(c,RC) \
        SIG_E3R(a,RA) SIG_E3R(b,RB) SIG_E3R(c,RC) \
    }

__global__ __launch_bounds__(192) __attribute__((amdgpu_waves_per_eu(1, 6)))
void sig_kernel(const float* __restrict__ x, __hip_bfloat16* __restrict__ feats) {
    __shared__ __align__(16) float X[66 * 8];
    __shared__ __align__(16) float PD[126 * 8];
    __shared__ float S2buf[WPB * 81];
    __shared__ float S1buf[WPB * 9];

    const int blk = blockIdx.x;
    const int b   = blk / SBLK;
    const int s0  = (blk % SBLK) * WPB;
    const int lo  = (s0 - 59 > 0) ? (s0 - 59) : 0;
    const int hi  = (s0 + WPB - 1 < NS - 1) ? (s0 + WPB - 1) : (NS - 1);
    const int nrow = hi - lo + 1;     // <= 66
    const int tid = threadIdx.x;

    {
        const float4* src = (const float4*)(x + ((size_t)b * NS + lo) * 8);
        float4* X4 = (float4*)X;
        const int n4 = nrow * 2;
        for (int t = tid; t < n4; t += 192) X4[t] = src[t];
    }
    __syncthreads();
    {
        const float4* X4 = (const float4*)X;
        float4* PD4 = (float4*)PD;
        for (int t = tid; t < 252; t += 192) {
            const int p = t >> 1;
            const int r = p - 59;
            float4 dv = {0.f, 0.f, 0.f, 0.f};
            if (r > 0 && r < nrow) {
                const float4 a = X4[t - 118], bb = X4[t - 120];
                dv.x = a.x - bb.x; dv.y = a.y - bb.y; dv.z = a.z - bb.z; dv.w = a.w - bb.w;
            }
            PD4[t] = dv;
        }
    }
    __syncthreads();

    const int t3    = tid >> 6;
    const int lt    = tid & 63;
    const int widx0 = lt / 9;
    const int ci    = lt - widx0 * 9;
    const bool act  = (lt < 63) && (s0 + widx0 < NS);
    const int widx  = (widx0 < WPB - 1) ? widx0 : WPB - 1;
    int s = s0 + widx; if (s > NS - 1) s = NS - 1;

    float S3sa=0.f, S3sb=0.f, S3sc=0.f;
    f32x2 S3pa0={0.f,0.f},S3pa1={0.f,0.f},S3pa2={0.f,0.f},S3pa3={0.f,0.f};
    f32x2 S3pb0={0.f,0.f},S3pb1={0.f,0.f},S3pb2={0.f,0.f},S3pb3={0.f,0.f};
    f32x2 S3pc0={0.f,0.f},S3pc1={0.f,0.f},S3pc2={0.f,0.f},S3pc3={0.f,0.f};
    float S2ra=0.f, S2rb=0.f, S2rc=0.f;
    float S1i = 0.f;
    const int ioff = (ci > 0) ? (ci - 1) : 0;
    const int sm59 = s - 59;
    const int g0   = (sm59 > 0) ? sm59 : 0;
    const float DT = 1.0f / 59.0f;

    if (t3 == 0)      { SIG_MAIN(v0,   e0.x, e0.y) }
    else if (t3 == 1) { SIG_MAIN(e0.z, e0.w, e1.x) }
    else              { SIG_MAIN(e1.y, e1.z, e1.w) }

    if (t3 == 0)      { SIG_ST(0,1,2) }
    else if (t3 == 1) { SIG_ST(3,4,5) }
    else              { SIG_ST(6,7,8) }
    __syncthreads();

    const float* s1p = &S1buf[widx * 9];
    const float s1v0=s1p[0], s1v1=s1p[1], s1v2=s1p[2], s1v3=s1p[3], s1v4=s1p[4];
    const float s1v5=s1p[5], s1v6=s1p[6], s1v7=s1p[7], s1v8=s1p[8];
    const float* S2w = &S2buf[widx * 81];
    const int tb = ci * 81;
    __hip_bfloat16* frow = feats + (size_t)(b * NS + s) * KPAD;

    if (t3 == 0)      { SIG_EMIT(0,1,2) }
    else if (t3 == 1) { SIG_EMIT(3,4,5) }
    else              { SIG_EMIT(6,7,8) }
}

// ============================================================================
// Fused weight prep (one launch): blocks 0..511 -> w1T; 512..767 -> w2g/gw/cvec
// ============================================================================
__global__ __launch_bounds__(512) void convert_weights(
        const float* __restrict__ w1, const float* __restrict__ w2,
        const float* __restrict__ lng, const float* __restrict__ lnb,
        const float* __restrict__ b2,
        __hip_bfloat16* __restrict__ w1T, __hip_bfloat16* __restrict__ w2g,
        float* __restrict__ gw, float* __restrict__ cvec) {
    const int blk = blockIdx.x;
    const int k = threadIdx.x;
    if (blk < 512) {
        if (k < KPAD) {
            const float v = (k < 285) ? w1[(size_t)k * H2 + blk] : 0.0f;
            w1T[(size_t)blk * KPAD + k] = __float2bfloat16(v);
        }
        return;
    }
    const int n = blk - 512;           // 0..255
    const float wv = w2[(size_t)k * HID + n];
    const float a = lng[k] * wv;
    const float c = lnb[k] * wv;
    w2g[(size_t)n * H2 + k] = __float2bfloat16(a);
    float ra = a, rc = c;
#pragma unroll
    for (int d = 1; d < 64; d <<= 1) { ra += __shfl_xor(ra, d); rc += __shfl_xor(rc, d); }
    __shared__ float r1[8], r2[8];
    const int wv_ = k >> 6, ln = k & 63;
    if (ln == 0) { r1[wv_] = ra; r2[wv_] = rc; }
    __syncthreads();
    if (k == 0) {
        float sa = 0.f, sc = 0.f;
#pragma unroll
        for (int i = 0; i < 8; ++i) { sa += r1[i]; sc += r2[i]; }
        gw[n] = sa; cvec[n] = sc + b2[n];
    }
}

// ============================================================================
// GEMM1 (A+B both LDS-resident, COALESCED staging, one barrier):
// r10 lesson: every A-frag global load was a 16-segment row-gather; four
// different K-loop structures all queue-starved at ~40us.  Now A-tile rows
// are copied row-major (fully coalesced), K-loop is 100% LDS: per wave per
// kt = 4 ds_read_b128 + 4 MFMA, no global, no barriers.
// block = 64M x 64N, 256 thr / 4 waves, wave tile 32x32.  LDS 75.8 KB.
// stats[row][32]: 16 sum-slots + 16 sq-slots (by*2 + N-half).
// ============================================================================
__global__ __launch_bounds__(256)
void gemm1_kernel(const __hip_bfloat16* __restrict__ feats,
                  const __hip_bfloat16* __restrict__ w1T,
                  const float* __restrict__ b1,
                  __hip_bfloat16* __restrict__ h1,
                  float* __restrict__ stats) {
    __shared__ __align__(16) __hip_bfloat16 ldsA[64 * KLDS1];   // 37888 B
    __shared__ __align__(16) __hip_bfloat16 ldsB[64 * KLDS1];   // 37888 B
    const int tid  = threadIdx.x;
    const int wave = tid >> 6;
    const int lane = tid & 63;
    const int quad = lane >> 4;
    const int l16  = lane & 15;
    const int m0   = blockIdx.x * 64;
    const int n0   = blockIdx.y * 64;

    for (int c = tid; c < 64 * 36; c += 256) {     // coalesced co-stage, once
        const int n = c / 36, k8 = c - n * 36;
        *(short8*)(ldsA + n * KLDS1 + k8 * 8) =
            *(const short8*)(feats + (size_t)(m0 + n) * KPAD + k8 * 8);
        *(short8*)(ldsB + n * KLDS1 + k8 * 8) =
            *(const short8*)(w1T + (size_t)(n0 + n) * KPAD + k8 * 8);
    }
    __syncthreads();

    const int mh = (wave >> 1) * 32;
    const int nh = (wave & 1) * 32;
    const __hip_bfloat16* ab = ldsA + (mh + l16) * KLDS1 + quad * 8;
    const __hip_bfloat16* bb = ldsB + (nh + l16) * KLDS1 + quad * 8;

    f32x4 acc00={0,0,0,0},acc01={0,0,0,0},acc10={0,0,0,0},acc11={0,0,0,0};
#pragma unroll
    for (int kt = 0; kt < 9; ++kt) {
        const int ko = kt * 32;
        const short8 av0 = *(const short8*)(ab + ko);
        const short8 av1 = *(const short8*)(ab + 16 * KLDS1 + ko);
        const short8 bv0 = *(const short8*)(bb + ko);
        const short8 bv1 = *(const short8*)(bb + 16 * KLDS1 + ko);
        acc00 = MFMA(av0, bv0, acc00); acc01 = MFMA(av0, bv1, acc01);
        acc10 = MFMA(av1, bv0, acc10); acc11 = MFMA(av1, bv1, acc11);
    }

    // bias + exact GELU (C frag: row = quad*4+r, col = l16)
    const float bias0 = b1[n0 + nh + l16];
    const float bias1 = b1[n0 + nh + 16 + l16];
#define G1G(A,B) { A[0]=geluf(A[0]+B); A[1]=geluf(A[1]+B); A[2]=geluf(A[2]+B); A[3]=geluf(A[3]+B); }
    G1G(acc00,bias0) G1G(acc01,bias1) G1G(acc10,bias0) G1G(acc11,bias1)
#undef G1G

    // per-row partials over this wave's 32 cols -> stats slot by*2 + N-half
    f32x4 s0 = acc00 + acc01, q0 = acc00*acc00 + acc01*acc01;
    f32x4 s1 = acc10 + acc11, q1 = acc10*acc10 + acc11*acc11;
    s0 += shfl4(s0,1); q0 += shfl4(q0,1); s1 += shfl4(s1,1); q1 += shfl4(q1,1);
    s0 += shfl4(s0,2); q0 += shfl4(q0,2); s1 += shfl4(s1,2); q1 += shfl4(q1,2);
    s0 += shfl4(s0,4); q0 += shfl4(q0,4); s1 += shfl4(s1,4); q1 += shfl4(q1,4);
    s0 += shfl4(s0,8); q0 += shfl4(q0,8); s1 += shfl4(s1,8); q1 += shfl4(q1,8);
    const int nb2 = blockIdx.y * 2 + (wave & 1);
    if (l16 == 0) {
#pragma unroll
        for (int r = 0; r < 4; ++r) {
            const int r0 = m0 + mh + quad * 4 + r;
            stats[r0 * 32 + nb2] = s0[r]; stats[r0 * 32 + 16 + nb2] = q0[r];
            const int r1 = r0 + 16;
            stats[r1 * 32 + nb2] = s1[r]; stats[r1 * 32 + 16 + nb2] = q1[r];
        }
    }

    // h1 store (raw GELU, bf16)
    {
        __hip_bfloat16* hp = h1 + (size_t)(m0 + mh + quad * 4) * H2;
        const int c0 = n0 + nh + l16;
#pragma unroll
        for (int r = 0; r < 4; ++r) {
            hp[(size_t)r * H2 + c0     ] = __float2bfloat16(acc00[r]);
            hp[(size_t)r * H2 + c0 + 16] = __float2bfloat16(acc01[r]);
        }
        __hip_bfloat16* hp2 = hp + (size_t)16 * H2;
#pragma unroll
        for (int r = 0; r < 4; ++r) {
            hp2[(size_t)r * H2 + c0     ] = __float2bfloat16(acc10[r]);
            hp2[(size_t)r * H2 + c0 + 16] = __float2bfloat16(acc11[r]);
        }
    }
}

// ============================================================================
// GEMM2 (A+B LDS-resident, coalesced staging, one barrier, LN folded):
// block = 64M x 32N, 256 thr / 4 waves, wave tile 16M x 32N.  LDS 99.8 KB
// (1 block/CU).  Per kt: 3 ds_read_b128 + 2 MFMA, fully unrolled K=512.
// out = rsv_m*(h1 @ w2g - mu_m*gw[n]) + cvec[n]
// ============================================================================
__global__ __launch_bounds__(256)
void gemm2_kernel(const __hip_bfloat16* __restrict__ h1,
                  const __hip_bfloat16* __restrict__ w2g,
                  const float* __restrict__ stats,
                  const float* __restrict__ gw,
                  const float* __restrict__ cvec,
                  float* __restrict__ out) {
    __shared__ __align__(16) __hip_bfloat16 ldsA[64 * KLDS2];   // 66560 B
    __shared__ __align__(16) __hip_bfloat16 ldsB[32 * KLDS2];   // 33280 B
    const int tid  = threadIdx.x;
    const int wave = tid >> 6;
    const int lane = tid & 63;
    const int quad = lane >> 4;
    const int l16  = lane & 15;
    const int m0   = blockIdx.x * 64;
    const int n0   = blockIdx.y * 32;

    for (int c = tid; c < 64 * 64; c += 256) {     // A co-stage (coalesced)
        const int n = c >> 6, k8 = c & 63;
        *(short8*)(ldsA + n * KLDS2 + k8 * 8) =
            *(const short8*)(h1 + (size_t)(m0 + n) * H2 + k8 * 8);
    }
    for (int c = tid; c < 32 * 64; c += 256) {     // B co-stage (coalesced)
        const int n = c >> 6, k8 = c & 63;
        *(short8*)(ldsB + n * KLDS2 + k8 * 8) =
            *(const short8*)(w2g + (size_t)(n0 + n) * H2 + k8 * 8);
    }
    __syncthreads();

    const int mh = wave * 16;
    const __hip_bfloat16* ab = ldsA + (mh + l16) * KLDS2 + quad * 8;
    const __hip_bfloat16* bb = ldsB + l16 * KLDS2 + quad * 8;

    f32x4 acc0={0,0,0,0}, acc1={0,0,0,0};
#pragma unroll
    for (int kt = 0; kt < 16; ++kt) {
        const int ko = kt * 32;
        const short8 av  = *(const short8*)(ab + ko);
        const short8 bv0 = *(const short8*)(bb + ko);
        const short8 bv1 = *(const short8*)(bb + 16 * KLDS2 + ko);
        acc0 = MFMA(av, bv0, acc0);
        acc1 = MFMA(av, bv1, acc1);
    }

    const int c0 = n0 + l16, c1 = c0 + 16;
    const float gw0 = gw[c0], gw1 = gw[c1];
    const float cv0 = cvec[c0], cv1 = cvec[c1];
    const int rbase = m0 + mh + quad * 4;
#pragma unroll
    for (int r = 0; r < 4; ++r) {
        const int row = rbase + r;
        const float* sp = &stats[row * 32];
        float su = 0.f, qu = 0.f;
#pragma unroll
        for (int i = 0; i < 4; ++i) {
            const float4 sv = *(const float4*)(sp + i * 4);
            const float4 qv = *(const float4*)(sp + 16 + i * 4);
            su += sv.x + sv.y + sv.z + sv.w;
            qu += qv.x + qv.y + qv.z + qv.w;
        }
        const float mu  = su * (1.0f / 512.0f);
        const float rsv = rsqrtf(qu * (1.0f / 512.0f) - mu * mu + 1e-5f);
        out[(size_t)row * HID + c0] = rsv * (acc0[r] - mu * gw0) + cv0;
        out[(size_t)row * HID + c1] = rsv * (acc1[r] - mu * gw1) + cv1;
    }
}

// ============================================================================
extern "C" void kernel_launch(void* const* d_in, const int* in_sizes, int n_in,
                              void* d_out, int out_size, void* d_ws, size_t ws_size,
                              hipStream_t stream) {
    const float* x   = (const float*)d_in[0];
    const float* w1  = (const float*)d_in[1];
    const float* b1  = (const float*)d_in[2];
    const float* lng = (const float*)d_in[3];
    const float* lnb = (const float*)d_in[4];
    const float* w2  = (const float*)d_in[5];
    const float* b2  = (const float*)d_in[6];
    float* out = (float*)d_out;

    char* ws = (char*)d_ws;
    __hip_bfloat16* feats = (__hip_bfloat16*)(ws);                        // 9437184
    __hip_bfloat16* h1    = (__hip_bfloat16*)(ws + 9437184);              // 16777216
    __hip_bfloat16* w1T   = (__hip_bfloat16*)(ws + 26214400);             // 294912
    __hip_bfloat16* w2g   = (__hip_bfloat16*)(ws + 26509312);             // 262144
    float*          gw    = (float*)(ws + 26771456);                      // 4096
    float*          cvec  = (float*)(ws + 26775552);                      // 4096
    float*          stats = (float*)(ws + 26779648);                      // 16384*32*4 = 2097152

    convert_weights<<<dim3(768), dim3(512), 0, stream>>>(w1, w2, lng, lnb, b2,
                                                         w1T, w2g, gw, cvec);
    sig_kernel<<<dim3(8 * SBLK), dim3(192), 0, stream>>>(x, feats);
    gemm1_kernel<<<dim3(256, 8), dim3(256), 0, stream>>>(feats, w1T, b1, h1, stats);
    gemm2_kernel<<<dim3(256, 8), dim3(256), 0, stream>>>(h1, w2g, stats, gw, cvec, out);
}